// Round 3
// baseline (8012.753 us; speedup 1.0000x reference)
//
#include <hip/hip_runtime.h>
#include <hip/hip_bf16.h>

// LSTM forward, T=512 B=128 D=1024 H=1024, fp32 in/out, bf16 MFMA compute.
//
// Round 3: kill same-address atomic contention in the grid barrier.
//  - arrival = relaxed sc1 STORE of epoch to a per-block 64B-padded slot
//    (no RMW -> no serialization at the coherent point)
//  - wait = threads 0..127 each poll ONE slot of the block's dependency
//    group in parallel (pure reads spread over 128 lines), then syncthreads
//  - two independent barrier groups by batch-half (mbase): h rows 0..63
//    only couple the 128 blocks with mbase=0, likewise 64..127
//  - t=0: h0 == 0, so skip h-part GEMM and the wait entirely
//  - everything else as round 2: W in LDS for all steps, h via sc1
//    (L2-bypass) loads/stores, XPART(t+1) overlaps arrival propagation,
//    4 independent MFMA chains, intra-wave gate exchange.

#define NT 512
#define NB 128
#define ND 1024
#define NH 1024
#define SLOT_U32 16   // 64B per slot line

typedef __attribute__((ext_vector_type(8))) __bf16 bf16x8;
typedef __attribute__((ext_vector_type(4))) float  f32x4;
typedef __attribute__((ext_vector_type(2))) unsigned long long ullx2;

__device__ __forceinline__ float sigm(float x) { return 1.0f / (1.0f + __expf(-x)); }
__device__ __forceinline__ float tanh_(float x) {
    x = fminf(15.0f, fmaxf(-15.0f, x));
    float e = __expf(-2.0f * x);
    return (1.0f - e) / (1.0f + e);
}

__global__ void __launch_bounds__(256, 1)
lstm_main(const float* __restrict__ x, const float* __restrict__ w_ih,
          const float* __restrict__ b_ih, const float* __restrict__ w_hh,
          const float* __restrict__ b_hh, float* __restrict__ out,
          unsigned short* __restrict__ h_bf, unsigned* __restrict__ slots)
{
    __shared__ uint4 ldsB[8192];       // [k8 0..255][c 0..31] bf16x8 chunks = 128 KiB
    __shared__ float scr[4][16][33];   // per-wave gate scratch (intra-wave exchange)

    const int tid  = threadIdx.x;
    const int lane = tid & 63;
    const int wid  = tid >> 6;
    const int bid  = blockIdx.x;

    const int xcd    = bid & 7;                 // consecutive blocks round-robin XCDs
    const int within = bid >> 3;                // 0..31
    const int grp    = within & 1;              // batch-half group
    const int mbase  = grp * 64;                // batch-row half
    const int jbase  = xcd * 128 + (within >> 1) * 8;  // 8 h-cols per block

    // slot this thread polls: the 128 blocks with the same grp
    const int pb = (tid & 7) + 8 * (2 * ((tid & 127) >> 3) + grp);

    // ---- one-time: W rows for this block's 8 h-cols x 4 gates -> bf16 -> LDS ----
    for (int idx = tid; idx < 8192; idx += 256) {
        const int c  = idx >> 8;
        const int k8 = idx & 255;
        const int grow = (c >> 3) * NH + jbase + (c & 7);
        const float* src = (k8 < 128) ? (w_ih + (size_t)grow * ND + k8 * 8)
                                      : (w_hh + (size_t)grow * NH + (k8 - 128) * 8);
        const float4 f0 = *(const float4*)src;
        const float4 f1 = *(const float4*)(src + 4);
        bf16x8 v;
        v[0] = (__bf16)f0.x; v[1] = (__bf16)f0.y; v[2] = (__bf16)f0.z; v[3] = (__bf16)f0.w;
        v[4] = (__bf16)f1.x; v[5] = (__bf16)f1.y; v[6] = (__bf16)f1.z; v[7] = (__bf16)f1.w;
        ldsB[k8 * 32 + c] = __builtin_bit_cast(uint4, v);
    }

    // cell assignment: lane owns (crow = lane>>2, jj2=(lane&3)*2) and jj2+1
    const int crow = lane >> 2;
    const int jj2  = (lane & 3) * 2;
    const int gb   = mbase + wid * 16 + crow;
    const int gj   = jbase + jj2;

    float bias[4][2];
    #pragma unroll
    for (int g = 0; g < 4; ++g)
        #pragma unroll
        for (int u = 0; u < 2; ++u)
            bias[g][u] = b_ih[g * NH + gj + u] + b_hh[g * NH + gj + u];
    float cst[2] = {0.f, 0.f};

    const int lrow  = mbase + wid * 16 + (lane & 15);  // A-frag batch row
    const int kslot = lane >> 4;                       // frag k-group
    const int bcol  = lane & 15;                       // B-frag column

    __syncthreads();   // weights staged

    f32x4 a0a = {0.f,0.f,0.f,0.f}, a0b = {0.f,0.f,0.f,0.f};
    f32x4 a1a = {0.f,0.f,0.f,0.f}, a1b = {0.f,0.f,0.f,0.f};

    // x-part GEMM for step tt (K=0..1023), 4 independent chains
    #define XPART(tt) do {                                                          \
        const float* xt = x + (size_t)(tt) * NB * ND + (size_t)lrow * ND + kslot*8; \
        _Pragma("unroll")                                                           \
        for (int kk = 0; kk < 32; ++kk) {                                           \
            const float4 f0 = *(const float4*)(xt + kk * 32);                       \
            const float4 f1 = *(const float4*)(xt + kk * 32 + 4);                   \
            bf16x8 a;                                                               \
            a[0]=(__bf16)f0.x; a[1]=(__bf16)f0.y; a[2]=(__bf16)f0.z; a[3]=(__bf16)f0.w; \
            a[4]=(__bf16)f1.x; a[5]=(__bf16)f1.y; a[6]=(__bf16)f1.z; a[7]=(__bf16)f1.w; \
            const int k8 = kk * 4 + kslot;                                          \
            const bf16x8 b0 = __builtin_bit_cast(bf16x8, ldsB[k8 * 32 + bcol]);     \
            const bf16x8 b1 = __builtin_bit_cast(bf16x8, ldsB[k8 * 32 + 16 + bcol]);\
            if (kk & 1) {                                                           \
                a0b = __builtin_amdgcn_mfma_f32_16x16x32_bf16(a, b0, a0b, 0,0,0);   \
                a1b = __builtin_amdgcn_mfma_f32_16x16x32_bf16(a, b1, a1b, 0,0,0);   \
            } else {                                                                \
                a0a = __builtin_amdgcn_mfma_f32_16x16x32_bf16(a, b0, a0a, 0,0,0);   \
                a1a = __builtin_amdgcn_mfma_f32_16x16x32_bf16(a, b1, a1a, 0,0,0);   \
            }                                                                       \
        }                                                                           \
    } while (0)

    XPART(0);

    for (int t = 0; t < NT; ++t) {
        if (t) {
            // ---- wait: my group's 128 blocks all posted epoch >= t ----
            if (tid < 128) {
                const unsigned* s = slots + (size_t)pb * SLOT_U32;
                while (__hip_atomic_load(s, __ATOMIC_RELAXED, __HIP_MEMORY_SCOPE_AGENT)
                       < (unsigned)t)
                    __builtin_amdgcn_s_sleep(1);
            }
            __syncthreads();

            // ---- h-part GEMM: K=1024..2047, h_{t-1} via sc1 loads ----
            const unsigned short* hb = h_bf + (size_t)(t & 1) * NB * NH
                                            + (size_t)lrow * NH + kslot * 8;
            #pragma unroll
            for (int kk = 0; kk < 32; ++kk) {
                ullx2 v;
                v[0] = __hip_atomic_load((const unsigned long long*)(const void*)(hb + kk * 32),
                                         __ATOMIC_RELAXED, __HIP_MEMORY_SCOPE_AGENT);
                v[1] = __hip_atomic_load((const unsigned long long*)(const void*)(hb + kk * 32 + 4),
                                         __ATOMIC_RELAXED, __HIP_MEMORY_SCOPE_AGENT);
                const bf16x8 a = __builtin_bit_cast(bf16x8, v);
                const int k8 = 128 + kk * 4 + kslot;
                const bf16x8 b0 = __builtin_bit_cast(bf16x8, ldsB[k8 * 32 + bcol]);
                const bf16x8 b1 = __builtin_bit_cast(bf16x8, ldsB[k8 * 32 + 16 + bcol]);
                if (kk & 1) {
                    a0b = __builtin_amdgcn_mfma_f32_16x16x32_bf16(a, b0, a0b, 0,0,0);
                    a1b = __builtin_amdgcn_mfma_f32_16x16x32_bf16(a, b1, a1b, 0,0,0);
                } else {
                    a0a = __builtin_amdgcn_mfma_f32_16x16x32_bf16(a, b0, a0a, 0,0,0);
                    a1a = __builtin_amdgcn_mfma_f32_16x16x32_bf16(a, b1, a1a, 0,0,0);
                }
            }
        }

        // ---- intra-wave gate exchange (C-layout: col=lane&15, row=(lane>>4)*4+r) ----
        {
            const f32x4 s0 = a0a + a0b;
            const f32x4 s1 = a1a + a1b;
            #pragma unroll
            for (int r = 0; r < 4; ++r) {
                scr[wid][kslot * 4 + r][bcol]      = s0[r];
                scr[wid][kslot * 4 + r][bcol + 16] = s1[r];
            }
        }

        // ---- cell update: lane finishes cells (crow, jj2) and (crow, jj2+1) ----
        float hv[2];
        #pragma unroll
        for (int u = 0; u < 2; ++u) {
            const float iv = sigm (scr[wid][crow][ 0 + jj2 + u] + bias[0][u]);
            const float fv = sigm (scr[wid][crow][ 8 + jj2 + u] + bias[1][u]);
            const float gv = tanh_(scr[wid][crow][16 + jj2 + u] + bias[2][u]);
            const float ov = sigm (scr[wid][crow][24 + jj2 + u] + bias[3][u]);
            const float cc = fv * cst[u] + iv * gv;
            cst[u] = cc;
            hv[u] = ov * tanh_(cc);
        }

        // ---- publish h_t: packed u32, sc1 store straight to coherent point ----
        {
            const unsigned short u0 = __builtin_bit_cast(unsigned short, (__bf16)hv[0]);
            const unsigned short u1 = __builtin_bit_cast(unsigned short, (__bf16)hv[1]);
            const unsigned hpack = (unsigned)u0 | ((unsigned)u1 << 16);
            unsigned* dst = (unsigned*)(void*)(h_bf + (size_t)((t + 1) & 1) * NB * NH
                                                    + (size_t)gb * NH + gj);
            __hip_atomic_store(dst, hpack, __ATOMIC_RELAXED, __HIP_MEMORY_SCOPE_AGENT);
        }

        // ---- arrive: syncthreads drains vmcnt => h stores are at L3 first ----
        __syncthreads();
        if (tid == 0)
            __hip_atomic_store(slots + (size_t)bid * SLOT_U32, (unsigned)(t + 1),
                               __ATOMIC_RELAXED, __HIP_MEMORY_SCOPE_AGENT);

        // ---- non-critical stores + next x-part overlap arrival propagation ----
        {
            float2 o; o.x = hv[0]; o.y = hv[1];
            *(float2*)&out[((size_t)t * NB + gb) * NH + gj] = o;
            if (t == NT - 1)
                *(float2*)&out[(size_t)NT * NB * NH + (size_t)gb * NH + gj] = o; // h_n
        }
        if (t + 1 < NT) {
            a0a = (f32x4){0.f,0.f,0.f,0.f}; a0b = (f32x4){0.f,0.f,0.f,0.f};
            a1a = (f32x4){0.f,0.f,0.f,0.f}; a1b = (f32x4){0.f,0.f,0.f,0.f};
            XPART(t + 1);
        }
    }

    // final cell state c_n
    {
        float2 cn; cn.x = cst[0]; cn.y = cst[1];
        *(float2*)&out[(size_t)NT * NB * NH + (size_t)NB * NH + (size_t)gb * NH + gj] = cn;
    }
}

extern "C" void kernel_launch(void* const* d_in, const int* in_sizes, int n_in,
                              void* d_out, int out_size, void* d_ws, size_t ws_size,
                              hipStream_t stream)
{
    const float* x    = (const float*)d_in[0];
    const float* w_ih = (const float*)d_in[1];
    const float* b_ih = (const float*)d_in[2];
    const float* w_hh = (const float*)d_in[3];
    const float* b_hh = (const float*)d_in[4];
    float* out = (float*)d_out;

    const size_t hbf_bytes  = (size_t)2 * NB * NH * sizeof(unsigned short);  // 512 KiB
    const size_t slot_bytes = (size_t)256 * SLOT_U32 * sizeof(unsigned);     // 16 KiB
    if (ws_size < hbf_bytes + slot_bytes) return;

    unsigned short* h_bf = (unsigned short*)d_ws;
    unsigned* slots = (unsigned*)((char*)d_ws + hbf_bytes);

    // only the slot epochs need zeroing each call (h0 term is skipped at t=0)
    hipMemsetAsync(slots, 0, slot_bytes, stream);

    void* args[] = { (void*)&x, (void*)&w_ih, (void*)&b_ih, (void*)&w_hh,
                     (void*)&b_hh, (void*)&out, (void*)&h_bf, (void*)&slots };
    hipError_t err = hipLaunchCooperativeKernel((const void*)lstm_main,
                                                dim3(256), dim3(256),
                                                args, 0, stream);
    if (err != hipSuccess) {
        // 256 blocks x 1 block/CU are co-resident on 256 CUs
        lstm_main<<<dim3(256), dim3(256), 0, stream>>>(x, w_ih, b_ih, w_hh,
                                                       b_hh, out, h_bf, slots);
    }
}

// Round 4
// 5123.206 us; speedup vs baseline: 1.5640x; 1.5640x over previous
//
#include <hip/hip_runtime.h>
#include <hip/hip_bf16.h>

// LSTM forward, T=512 B=128 D=1024 H=1024, fp32 in/out, bf16 MFMA compute.
//
// Round 4: producer/consumer wave specialization + tiled (coalesced) h.
//  - 256 blocks x 512 threads (8 waves, 2/SIMD). Waves 0-3 = H engine
//    (recurrent GEMM + cell + publish), waves 4-7 = X engine (x-projection
//    for step t+1 -> LDS gx ping-pong). Period = max(X,H), not X+H.
//  - h stored TILED [k8][row][8] so the MFMA A-frag load is one contiguous
//    16B per lane, coalesced across lanes (was 2KB-strided 8B loads).
//  - depth-16 explicit staging of h loads (16 x 16B in flight).
//  - per-wave publish: sc1 stores -> s_waitcnt vmcnt(0) -> LDS arrival
//    counter; 4th H wave posts the block's slot (no X-engine stall).
//  - weights in LDS all 512 steps; gx in LDS; one __syncthreads per step.

#define NT 512
#define NB 128
#define ND 1024
#define NH 1024
#define SLOT_U32 16   // 64B per block slot line

typedef __attribute__((ext_vector_type(8))) __bf16 bf16x8;
typedef __attribute__((ext_vector_type(4))) float  f32x4;
typedef __attribute__((ext_vector_type(2))) unsigned long long ullx2;
typedef unsigned long long u64;

__device__ __forceinline__ float sigm(float x) { return 1.0f / (1.0f + __expf(-x)); }
__device__ __forceinline__ float tanh_(float x) {
    x = fminf(15.0f, fmaxf(-15.0f, x));
    float e = __expf(-2.0f * x);
    return (1.0f - e) / (1.0f + e);
}

__global__ void __launch_bounds__(512, 2)
lstm_main(const float* __restrict__ x, const float* __restrict__ w_ih,
          const float* __restrict__ b_ih, const float* __restrict__ w_hh,
          const float* __restrict__ b_hh, float* __restrict__ out,
          unsigned short* __restrict__ h_t8,   // tiled: [2][k8 0..127][row 0..127][8]
          unsigned* __restrict__ slots)
{
    __shared__ uint4  ldsB[8192];          // 128 KiB weights: [k8 0..255][c 0..31]
    __shared__ f32x4  gxbuf[2][4][64][2];  // 16 KiB x-projection ping-pong
    __shared__ float  scr[4][16][33];      // 8.25 KiB gate exchange (H waves)
    __shared__ unsigned arrive;            // monotonic H-wave arrival counter

    const int tid  = threadIdx.x;
    const int lane = tid & 63;
    const int gwid = tid >> 6;        // 0..7
    const int wid  = gwid & 3;        // role-local wave id
    const bool isH = (gwid < 4);
    const int bid  = blockIdx.x;

    const int xcd    = bid & 7;                 // consecutive blocks round-robin XCDs
    const int within = bid >> 3;                // 0..31
    const int grp    = within & 1;              // batch-half group
    const int mbase  = grp * 64;
    const int jbase  = xcd * 128 + (within >> 1) * 8;  // 8 h-cols per block

    if (tid == 0) arrive = 0u;

    // ---- one-time: W rows for this block's 8 h-cols x 4 gates -> bf16 -> LDS ----
    for (int idx = tid; idx < 8192; idx += 512) {
        const int c  = idx >> 8;
        const int k8 = idx & 255;
        const int grow = (c >> 3) * NH + jbase + (c & 7);
        const float* src = (k8 < 128) ? (w_ih + (size_t)grow * ND + k8 * 8)
                                      : (w_hh + (size_t)grow * NH + (k8 - 128) * 8);
        const float4 f0 = *(const float4*)src;
        const float4 f1 = *(const float4*)(src + 4);
        bf16x8 v;
        v[0]=(__bf16)f0.x; v[1]=(__bf16)f0.y; v[2]=(__bf16)f0.z; v[3]=(__bf16)f0.w;
        v[4]=(__bf16)f1.x; v[5]=(__bf16)f1.y; v[6]=(__bf16)f1.z; v[7]=(__bf16)f1.w;
        ldsB[k8 * 32 + c] = __builtin_bit_cast(uint4, v);
    }

    const int lrow  = mbase + wid * 16 + (lane & 15);  // A-frag batch row
    const int kslot = lane >> 4;                       // frag k-group
    const int bcol  = lane & 15;                       // B-frag column

    // H-engine cell constants
    const int crow = lane >> 2;
    const int jj2  = (lane & 3) * 2;
    const int gb   = mbase + wid * 16 + crow;
    const int gj   = jbase + jj2;
    float bias[4][2], cst[2] = {0.f, 0.f};
    if (isH) {
        #pragma unroll
        for (int g = 0; g < 4; ++g)
            #pragma unroll
            for (int u = 0; u < 2; ++u)
                bias[g][u] = b_ih[g * NH + gj + u] + b_hh[g * NH + gj + u];
    }

    __syncthreads();   // weights staged, arrive=0 visible

    // x-projection for step tt -> gxbuf[buf] (X waves only)
    #define XPART(tt, buf) do {                                                     \
        f32x4 c0a={0,0,0,0}, c0b={0,0,0,0}, c1a={0,0,0,0}, c1b={0,0,0,0};           \
        const float* xt = x + (size_t)(tt)*NB*ND + (size_t)lrow*ND + kslot*8;       \
        _Pragma("unroll")                                                           \
        for (int kk = 0; kk < 32; ++kk) {                                           \
            const float4 f0 = *(const float4*)(xt + kk * 32);                       \
            const float4 f1 = *(const float4*)(xt + kk * 32 + 4);                   \
            bf16x8 a;                                                               \
            a[0]=(__bf16)f0.x; a[1]=(__bf16)f0.y; a[2]=(__bf16)f0.z; a[3]=(__bf16)f0.w; \
            a[4]=(__bf16)f1.x; a[5]=(__bf16)f1.y; a[6]=(__bf16)f1.z; a[7]=(__bf16)f1.w; \
            const int k8 = kk * 4 + kslot;                                          \
            const bf16x8 b0 = __builtin_bit_cast(bf16x8, ldsB[k8 * 32 + bcol]);     \
            const bf16x8 b1 = __builtin_bit_cast(bf16x8, ldsB[k8 * 32 + 16 + bcol]);\
            if (kk & 1) {                                                           \
                c0b = __builtin_amdgcn_mfma_f32_16x16x32_bf16(a, b0, c0b, 0,0,0);   \
                c1b = __builtin_amdgcn_mfma_f32_16x16x32_bf16(a, b1, c1b, 0,0,0);   \
            } else {                                                                \
                c0a = __builtin_amdgcn_mfma_f32_16x16x32_bf16(a, b0, c0a, 0,0,0);   \
                c1a = __builtin_amdgcn_mfma_f32_16x16x32_bf16(a, b1, c1a, 0,0,0);   \
            }                                                                       \
        }                                                                           \
        gxbuf[buf][wid][lane][0] = c0a + c0b;                                       \
        gxbuf[buf][wid][lane][1] = c1a + c1b;                                       \
    } while (0)

    if (!isH) XPART(0, 0);   // prologue: gx[0]
    __syncthreads();

    for (int t = 0; t < NT; ++t) {
        if (isH) {
            f32x4 acc0 = gxbuf[t & 1][wid][lane][0];
            f32x4 acc1 = gxbuf[t & 1][wid][lane][1];

            if (t) {
                // ---- poll: my group's 128 blocks posted epoch >= t (2 slots/lane) ----
                const int i1 = lane + 64;
                const unsigned* p0 = slots + (size_t)((lane & 7) + 8*(2*(lane >> 3) + grp)) * SLOT_U32;
                const unsigned* p1 = slots + (size_t)((i1 & 7)   + 8*(2*(i1 >> 3)   + grp)) * SLOT_U32;
                while (__hip_atomic_load(p0, __ATOMIC_RELAXED, __HIP_MEMORY_SCOPE_AGENT) < (unsigned)t ||
                       __hip_atomic_load(p1, __ATOMIC_RELAXED, __HIP_MEMORY_SCOPE_AGENT) < (unsigned)t)
                    __builtin_amdgcn_s_sleep(1);

                // ---- h-GEMM: K=1024 from tiled h, depth-16 staged sc1 loads ----
                f32x4 acc0b = {0,0,0,0}, acc1b = {0,0,0,0};
                const u64* hl = (const u64*)(const void*)(h_t8 + (size_t)(t & 1) * NB * NH)
                                + (size_t)lrow * 2;
                u64 st[16][2];
                #pragma unroll
                for (int kk = 0; kk < 16; ++kk) {
                    const int k8 = kk * 4 + kslot;
                    st[kk][0] = __hip_atomic_load(hl + (size_t)k8 * 256,
                                                  __ATOMIC_RELAXED, __HIP_MEMORY_SCOPE_AGENT);
                    st[kk][1] = __hip_atomic_load(hl + (size_t)k8 * 256 + 1,
                                                  __ATOMIC_RELAXED, __HIP_MEMORY_SCOPE_AGENT);
                }
                #pragma unroll
                for (int kk = 0; kk < 16; ++kk) {
                    ullx2 v; v[0] = st[kk][0]; v[1] = st[kk][1];
                    const int k8n = (kk + 16) * 4 + kslot;
                    st[kk][0] = __hip_atomic_load(hl + (size_t)k8n * 256,
                                                  __ATOMIC_RELAXED, __HIP_MEMORY_SCOPE_AGENT);
                    st[kk][1] = __hip_atomic_load(hl + (size_t)k8n * 256 + 1,
                                                  __ATOMIC_RELAXED, __HIP_MEMORY_SCOPE_AGENT);
                    const bf16x8 a = __builtin_bit_cast(bf16x8, v);
                    const int k8 = kk * 4 + kslot;
                    const bf16x8 b0 = __builtin_bit_cast(bf16x8, ldsB[(128 + k8) * 32 + bcol]);
                    const bf16x8 b1 = __builtin_bit_cast(bf16x8, ldsB[(128 + k8) * 32 + 16 + bcol]);
                    if (kk & 1) {
                        acc0b = __builtin_amdgcn_mfma_f32_16x16x32_bf16(a, b0, acc0b, 0,0,0);
                        acc1b = __builtin_amdgcn_mfma_f32_16x16x32_bf16(a, b1, acc1b, 0,0,0);
                    } else {
                        acc0  = __builtin_amdgcn_mfma_f32_16x16x32_bf16(a, b0, acc0, 0,0,0);
                        acc1  = __builtin_amdgcn_mfma_f32_16x16x32_bf16(a, b1, acc1, 0,0,0);
                    }
                }
                #pragma unroll
                for (int kk = 16; kk < 32; ++kk) {
                    ullx2 v; v[0] = st[kk - 16][0]; v[1] = st[kk - 16][1];
                    const bf16x8 a = __builtin_bit_cast(bf16x8, v);
                    const int k8 = kk * 4 + kslot;
                    const bf16x8 b0 = __builtin_bit_cast(bf16x8, ldsB[(128 + k8) * 32 + bcol]);
                    const bf16x8 b1 = __builtin_bit_cast(bf16x8, ldsB[(128 + k8) * 32 + 16 + bcol]);
                    if (kk & 1) {
                        acc0b = __builtin_amdgcn_mfma_f32_16x16x32_bf16(a, b0, acc0b, 0,0,0);
                        acc1b = __builtin_amdgcn_mfma_f32_16x16x32_bf16(a, b1, acc1b, 0,0,0);
                    } else {
                        acc0  = __builtin_amdgcn_mfma_f32_16x16x32_bf16(a, b0, acc0, 0,0,0);
                        acc1  = __builtin_amdgcn_mfma_f32_16x16x32_bf16(a, b1, acc1, 0,0,0);
                    }
                }
                acc0 += acc0b; acc1 += acc1b;
            }

            // ---- intra-wave gate exchange (C-layout: col=lane&15, row=(lane>>4)*4+r) ----
            #pragma unroll
            for (int r = 0; r < 4; ++r) {
                scr[wid][kslot * 4 + r][bcol]      = acc0[r];
                scr[wid][kslot * 4 + r][bcol + 16] = acc1[r];
            }

            // ---- cell update ----
            float hv[2];
            #pragma unroll
            for (int u = 0; u < 2; ++u) {
                const float iv = sigm (scr[wid][crow][ 0 + jj2 + u] + bias[0][u]);
                const float fv = sigm (scr[wid][crow][ 8 + jj2 + u] + bias[1][u]);
                const float gv = tanh_(scr[wid][crow][16 + jj2 + u] + bias[2][u]);
                const float ov = sigm (scr[wid][crow][24 + jj2 + u] + bias[3][u]);
                const float cc = fv * cst[u] + iv * gv;
                cst[u] = cc;
                hv[u] = ov * tanh_(cc);
            }

            // ---- publish h_t (tiled layout, buffer (t+1)&1), sc1 to L3 ----
            {
                const unsigned short u0 = __builtin_bit_cast(unsigned short, (__bf16)hv[0]);
                const unsigned short u1 = __builtin_bit_cast(unsigned short, (__bf16)hv[1]);
                const unsigned hpack = (unsigned)u0 | ((unsigned)u1 << 16);
                unsigned* dst = (unsigned*)(void*)(h_t8 + (size_t)((t + 1) & 1) * NB * NH
                                                   + ((size_t)(gj >> 3) * NB + gb) * 8 + (gj & 7));
                __hip_atomic_store(dst, hpack, __ATOMIC_RELAXED, __HIP_MEMORY_SCOPE_AGENT);
            }

            // ---- per-wave drain, LDS arrive; 4th wave posts block slot ----
            asm volatile("s_waitcnt vmcnt(0)" ::: "memory");
            if (lane == 0) {
                const unsigned prev = atomicAdd(&arrive, 1u);
                if (prev == 4u * (unsigned)t + 3u)
                    __hip_atomic_store(slots + (size_t)bid * SLOT_U32, (unsigned)(t + 1),
                                       __ATOMIC_RELAXED, __HIP_MEMORY_SCOPE_AGENT);
            }

            // ---- out stores (off critical path) ----
            {
                float2 o; o.x = hv[0]; o.y = hv[1];
                *(float2*)&out[((size_t)t * NB + gb) * NH + gj] = o;
                if (t == NT - 1)
                    *(float2*)&out[(size_t)NT * NB * NH + (size_t)gb * NH + gj] = o; // h_n
            }
        } else {
            if (t + 1 < NT) XPART(t + 1, (t + 1) & 1);   // X engine: next step's gx
        }
        __syncthreads();   // gx[t+1] ready; gx[t] fully consumed
    }

    // final cell state c_n
    if (isH) {
        float2 cn; cn.x = cst[0]; cn.y = cst[1];
        *(float2*)&out[(size_t)NT * NB * NH + (size_t)NB * NH + (size_t)gb * NH + gj] = cn;
    }
}

extern "C" void kernel_launch(void* const* d_in, const int* in_sizes, int n_in,
                              void* d_out, int out_size, void* d_ws, size_t ws_size,
                              hipStream_t stream)
{
    const float* x    = (const float*)d_in[0];
    const float* w_ih = (const float*)d_in[1];
    const float* b_ih = (const float*)d_in[2];
    const float* w_hh = (const float*)d_in[3];
    const float* b_hh = (const float*)d_in[4];
    float* out = (float*)d_out;

    const size_t hbf_bytes  = (size_t)2 * NB * NH * sizeof(unsigned short);  // 512 KiB
    const size_t slot_bytes = (size_t)256 * SLOT_U32 * sizeof(unsigned);     // 16 KiB
    if (ws_size < hbf_bytes + slot_bytes) return;

    unsigned short* h_t8 = (unsigned short*)d_ws;
    unsigned* slots = (unsigned*)((char*)d_ws + hbf_bytes);

    // only slot epochs need zeroing (t=0 skips the h read; h buffers are
    // fully rewritten before first read, gated by slots)
    hipMemsetAsync(slots, 0, slot_bytes, stream);

    void* args[] = { (void*)&x, (void*)&w_ih, (void*)&b_ih, (void*)&w_hh,
                     (void*)&b_hh, (void*)&out, (void*)&h_t8, (void*)&slots };
    hipError_t err = hipLaunchCooperativeKernel((const void*)lstm_main,
                                                dim3(256), dim3(512),
                                                args, 0, stream);
    if (err != hipSuccess) {
        // 256 blocks x 1 block/CU (LDS-bound) are co-resident on 256 CUs
        lstm_main<<<dim3(256), dim3(512), 0, stream>>>(x, w_ih, b_ih, w_hh,
                                                       b_hh, out, h_t8, slots);
    }
}